// Round 2
// baseline (717.829 us; speedup 1.0000x reference)
//
#include <hip/hip_runtime.h>
#include <math.h>

#define NS 4096
#define NF 512
#define NB 16
#define NC 10
#define HS 8192          // hash slots per column (pow2), load factor 0.5
#define HMASK 8191
#define HEMPTY 0xFFFFFFFFu

// ws layout: [0, 524288) float stats[8192][16]  (0 sum,1 sumsq,2 sumabs,3 nan,4 maxabs,5..14 csum)
//            [524288, 524928) int counts[16][10]
#define STATS_BYTES (NB * NF * 16 * 4)

// ---------------- K1: per-(b,c) class counts ----------------
__global__ void count_classes_kernel(const int* __restrict__ y, int* __restrict__ counts) {
    __shared__ int hist[NC];
    const int b = blockIdx.x >> 3;
    const int chunk = blockIdx.x & 7;
    if (threadIdx.x < NC) hist[threadIdx.x] = 0;
    __syncthreads();
    const int s0 = chunk * 512;
    for (int s = s0 + threadIdx.x; s < s0 + 512; s += 256)
        atomicAdd(&hist[y[b * NS + s]], 1);
    __syncthreads();
    if (threadIdx.x < NC) atomicAdd(&counts[b * NC + threadIdx.x], hist[threadIdx.x]);
}

// ---------------- K2: coalesced moments + class-sums ----------------
// grid = 16 b x 16 schunk x 2 fhalf = 512 blocks; thread owns one feature, walks 256 rows.
// y is wave-uniform here -> class dispatch is scalar branches, 1 v_add per element.
__launch_bounds__(256)
__global__ void stats_pass_kernel(const float* __restrict__ X,
                                  const int* __restrict__ y,
                                  float* __restrict__ statsb) {
    const int w  = blockIdx.x;
    const int b  = w >> 5;
    const int sc = (w >> 1) & 15;
    const int fh = w & 1;
    const int f  = fh * 256 + threadIdx.x;

    const float* Xp = X + ((size_t)b * NS + (size_t)sc * 256) * NF + f;
    const int*   yp = y + b * NS + sc * 256;

    float sum = 0.f, sumsq = 0.f, sumabs = 0.f, nancnt = 0.f, maxab = 0.f;
    float cs[NC];
    #pragma unroll
    for (int c = 0; c < NC; c++) cs[c] = 0.f;

    #pragma unroll 4
    for (int r = 0; r < 256; ++r) {
        float x = Xp[(size_t)r * NF];
        const int yv = __builtin_amdgcn_readfirstlane(yp[r]);   // wave-uniform -> SGPR
        if (x != x) { nancnt += 1.f; x = 0.f; }
        sum += x;
        sumsq = fmaf(x, x, sumsq);
        const float a = fabsf(x);
        sumabs += a;
        maxab = fmaxf(maxab, a);
        #pragma unroll
        for (int c = 0; c < NC; c++)
            if (yv == c) cs[c] += x;                            // scalar-branch guarded
    }

    float* sp = statsb + ((size_t)(b * NF + f)) * 16;
    atomicAdd(sp + 0, sum);
    atomicAdd(sp + 1, sumsq);
    atomicAdd(sp + 2, sumabs);
    atomicAdd(sp + 3, nancnt);
    atomicMax((int*)(sp + 4), __float_as_int(maxab));           // maxab >= 0: int order == float order
    #pragma unroll
    for (int c = 0; c < NC; c++) atomicAdd(sp + 5 + c, cs[c]);
}

// ---------------- helpers ----------------
__device__ __forceinline__ int wave_reduce_add_i(int v) {
    #pragma unroll
    for (int off = 32; off > 0; off >>= 1) v += __shfl_down(v, off, 64);
    return v;
}

__device__ __forceinline__ void hash_insert(unsigned int* hbase, float x, int& u) {
    if (x != x) x = 0.f;                        // nan_to_num before unique-count
    unsigned int pat = __float_as_uint(x);
    if (pat == 0x80000000u) pat = 0u;           // -0.0 == +0.0
    unsigned int slot = (pat * 2654435761u) >> 19;
    for (;;) {
        const unsigned int old = atomicCAS(hbase + slot, HEMPTY, pat);
        if (old == HEMPTY) { u++; break; }
        if (old == pat) break;
        slot = (slot + 1) & HMASK;
    }
}

// ---------------- K3: 4-column hash unique + finalize + MLP ----------------
__launch_bounds__(256)
__global__ void unique_mlp_kernel(const float* __restrict__ X,
                                  const float* __restrict__ statsb,
                                  const int* __restrict__ counts,
                                  const float* __restrict__ w1,
                                  const float* __restrict__ b1,
                                  const float* __restrict__ w2,
                                  const float* __restrict__ b2,
                                  float* __restrict__ out) {
    __shared__ unsigned int hash[4][HS];        // 128 KB
    __shared__ float sld[4][16];
    __shared__ float cld[NC];
    __shared__ int   redu[4][4];
    __shared__ float st_s[6];
    __shared__ float h_s[64];

    const int w  = blockIdx.x;                   // [0, 2048)
    const int g4 = (w & 7) * 256 + (w >> 3);     // XCD-contiguous column groups
    const int b  = g4 >> 7;
    const int f0 = (g4 << 2) & (NF - 1);
    const int tid = threadIdx.x;

    // init hashes (vectorized) + prefetch stats/counts into LDS
    uint4* hp = (uint4*)&hash[0][0];
    #pragma unroll
    for (int i = 0; i < (4 * HS / 4) / 256; i++)
        hp[tid + i * 256] = make_uint4(HEMPTY, HEMPTY, HEMPTY, HEMPTY);
    if (tid < 64) ((float*)sld)[tid] = statsb[(size_t)g4 * 64 + tid];
    if (tid >= 64 && tid < 64 + NC) cld[tid - 64] = (float)counts[b * NC + (tid - 64)];
    __syncthreads();

    const float* Xb = X + ((size_t)b * NS) * NF + f0;
    int uniq[4] = {0, 0, 0, 0};

    #pragma unroll
    for (int i0 = 0; i0 < 16; i0 += 4) {
        float4 v[4];
        #pragma unroll
        for (int k = 0; k < 4; k++) {
            const int s = (i0 + k) * 256 + tid;
            v[k] = *(const float4*)(Xb + (size_t)s * NF);
        }
        #pragma unroll
        for (int k = 0; k < 4; k++) {
            hash_insert(hash[0], v[k].x, uniq[0]);
            hash_insert(hash[1], v[k].y, uniq[1]);
            hash_insert(hash[2], v[k].z, uniq[2]);
            hash_insert(hash[3], v[k].w, uniq[3]);
        }
    }

    const int wave = tid >> 6, lane = tid & 63;
    #pragma unroll
    for (int c = 0; c < 4; c++) {
        const int u = wave_reduce_add_i(uniq[c]);
        if (lane == 0) redu[wave][c] = u;
    }
    __syncthreads();

    const float invS = 1.f / (float)NS;
    #pragma unroll
    for (int c = 0; c < 4; c++) {
        if (tid == 0) {
            const float n_unique = (float)(redu[0][c] + redu[1][c] + redu[2][c] + redu[3][c]);
            const float sum      = sld[c][0];
            const float gmean    = sum * invS;
            const float variance = fmaxf(sld[c][1] * invS - gmean * gmean, 0.f);
            const float mean_abs = sld[c][2] * invS;
            const float missing  = sld[c][3] * invS;
            const float max_abs  = sld[c][4];
            float between = 0.f;
            #pragma unroll
            for (int cc = 0; cc < NC; cc++) {
                const float cnt = cld[cc];
                const float cm  = sld[c][5 + cc] / fmaxf(cnt, 1.f);
                const float d   = cm - gmean;
                between += cnt * d * d;
            }
            between *= invS;
            const float target = between / fmaxf(variance, 1e-6f);
            float st[6] = { target, missing, n_unique * invS, variance, mean_abs, max_abs };
            #pragma unroll
            for (int i = 0; i < 6; i++) {
                float vv = st[i];
                if (!(fabsf(vv) < INFINITY)) vv = 0.f;
                st_s[i] = vv;
            }
        }
        __syncthreads();
        if (tid < 64) {
            float z = b1[tid];
            #pragma unroll
            for (int i = 0; i < 6; i++) z = fmaf(st_s[i], w1[i * 64 + tid], z);
            h_s[tid] = 0.5f * z * (1.f + erff(z * 0.70710678118654752440f));
        }
        __syncthreads();
        if (tid < 128) {
            float o = b2[tid];
            #pragma unroll
            for (int j = 0; j < 64; j++) o = fmaf(h_s[j], w2[j * 128 + tid], o);
            out[((size_t)(g4 * 4 + c)) * 128 + tid] = o;
        }
        __syncthreads();
    }
}

extern "C" void kernel_launch(void* const* d_in, const int* in_sizes, int n_in,
                              void* d_out, int out_size, void* d_ws, size_t ws_size,
                              hipStream_t stream) {
    const float* X  = (const float*)d_in[0];
    const int*   y  = (const int*)d_in[1];
    const float* w1 = (const float*)d_in[2];
    const float* b1 = (const float*)d_in[3];
    const float* w2 = (const float*)d_in[4];
    const float* b2 = (const float*)d_in[5];
    float* out     = (float*)d_out;
    float* statsb  = (float*)d_ws;
    int*   counts  = (int*)((char*)d_ws + STATS_BYTES);

    hipMemsetAsync(d_ws, 0, STATS_BYTES + NB * NC * 4, stream);
    count_classes_kernel<<<NB * 8, 256, 0, stream>>>(y, counts);
    stats_pass_kernel<<<NB * 16 * 2, 256, 0, stream>>>(X, y, statsb);
    unique_mlp_kernel<<<NB * NF / 4, 256, 0, stream>>>(X, statsb, counts, w1, b1, w2, b2, out);
}

// Round 3
// 412.059 us; speedup vs baseline: 1.7421x; 1.7421x over previous
//
#include <hip/hip_runtime.h>
#include <math.h>

#define NS 4096
#define NF 512
#define NB 16
#define NC 10
#define HS 6144           // hash slots (lf = 4096/6144 = 0.67), initial slot via umulhi
#define HEMPTY 0xFFFFFFFFu

__device__ __forceinline__ float wave_reduce_add(float v) {
    #pragma unroll
    for (int off = 32; off > 0; off >>= 1) v += __shfl_down(v, off, 64);
    return v;
}
__device__ __forceinline__ float wave_reduce_max(float v) {
    #pragma unroll
    for (int off = 32; off > 0; off >>= 1) v = fmaxf(v, __shfl_down(v, off, 64));
    return v;
}

// one 256-thread workgroup per (b, f) column; everything fused, no workspace.
__launch_bounds__(256)
__global__ void fused_all_kernel(const float* __restrict__ X,
                                 const int* __restrict__ y,
                                 const float* __restrict__ w1,
                                 const float* __restrict__ b1,
                                 const float* __restrict__ w2,
                                 const float* __restrict__ b2,
                                 float* __restrict__ out) {
    __shared__ unsigned int hash[HS];      // 24576 B
    __shared__ float red[4][16];           // per-wave partials: 6 moments + 10 csum
    __shared__ int   redc[4][NC];          // per-wave class counts
    __shared__ float stats_s[6];
    __shared__ float h_s[64];

    // XCD-aware swizzle: consecutive columns (sharing cache lines) stay on one XCD
    const int w = blockIdx.x;
    const int g = (w & 7) * 1024 + (w >> 3);   // bijection over [0, 8192)
    const int b = g >> 9;
    const int f = g & (NF - 1);
    const int tid = threadIdx.x;

    // init hash (vectorized): 6144 uints = 1536 uint4
    {
        uint4* hp = (uint4*)hash;
        #pragma unroll
        for (int i = 0; i < (HS / 4) / 256; i++)
            hp[tid + i * 256] = make_uint4(HEMPTY, HEMPTY, HEMPTY, HEMPTY);
    }
    __syncthreads();

    const float* Xp = X + (size_t)b * NS * NF + f;
    const int*   yp = y + b * NS;

    float sum = 0.f, sumsq = 0.f, sumabs = 0.f, maxabs = 0.f, nancnt = 0.f;
    int uniq = 0;
    float csum[NC];
    int   ccnt[NC];
    #pragma unroll
    for (int c = 0; c < NC; c++) { csum[c] = 0.f; ccnt[c] = 0; }

    #pragma unroll
    for (int k0 = 0; k0 < 16; k0 += 8) {
        float xv[8]; int yv[8];
        #pragma unroll
        for (int k = 0; k < 8; k++) {          // 8-deep load batch for MLP-in-flight
            const int s = (k0 + k) * 256 + tid;
            xv[k] = Xp[(size_t)s * NF];
            yv[k] = yp[s];
        }
        #pragma unroll
        for (int k = 0; k < 8; k++) {
            float x = xv[k];
            if (x != x) { nancnt += 1.f; x = 0.f; }   // nan_to_num
            sum += x;
            sumsq = fmaf(x, x, sumsq);
            const float a = fabsf(x);
            sumabs += a;
            maxabs = fmaxf(maxabs, a);
            const int yc = yv[k];
            #pragma unroll
            for (int c = 0; c < NC; c++) {
                const bool p = (yc == c);
                csum[c] += p ? x : 0.f;                       // VALU (cmp shared below)
                ccnt[c] += (int)__popcll(__ballot(p));        // SALU accumulate, wave-uniform
            }
            // distinct-value insert (-0.0 == +0.0, NaN already zeroed)
            unsigned int pat = __float_as_uint(x);
            if (pat == 0x80000000u) pat = 0u;
            unsigned int slot = __umulhi(pat * 2654435761u, HS);
            for (;;) {
                const unsigned int old = atomicCAS(&hash[slot], HEMPTY, pat);
                if (old == HEMPTY) { uniq++; break; }
                if (old == pat) break;
                if (++slot == HS) slot = 0;
            }
        }
    }

    sum    = wave_reduce_add(sum);
    sumsq  = wave_reduce_add(sumsq);
    sumabs = wave_reduce_add(sumabs);
    nancnt = wave_reduce_add(nancnt);
    float uq = wave_reduce_add((float)uniq);
    maxabs = wave_reduce_max(maxabs);
    #pragma unroll
    for (int c = 0; c < NC; c++) csum[c] = wave_reduce_add(csum[c]);

    const int wave = tid >> 6, lane = tid & 63;
    if (lane == 0) {
        red[wave][0] = sum;    red[wave][1] = sumsq; red[wave][2] = sumabs;
        red[wave][3] = nancnt; red[wave][4] = uq;    red[wave][5] = maxabs;
        #pragma unroll
        for (int c = 0; c < NC; c++) red[wave][6 + c] = csum[c];
        #pragma unroll
        for (int c = 0; c < NC; c++) redc[wave][c] = ccnt[c];   // ballot sums: per-wave totals
    }
    __syncthreads();

    if (tid == 0) {
        float t[16];
        int   cnts[NC];
        #pragma unroll
        for (int v = 0; v < 16; v++) t[v] = red[0][v];
        #pragma unroll
        for (int c = 0; c < NC; c++) cnts[c] = redc[0][c];
        #pragma unroll
        for (int wv = 1; wv < 4; wv++) {
            #pragma unroll
            for (int v = 0; v < 16; v++) {
                if (v == 5) t[v] = fmaxf(t[v], red[wv][v]);
                else        t[v] += red[wv][v];
            }
            #pragma unroll
            for (int c = 0; c < NC; c++) cnts[c] += redc[wv][c];
        }
        const float invS = 1.f / (float)NS;
        const float gmean    = t[0] * invS;
        const float variance = fmaxf(t[1] * invS - gmean * gmean, 0.f);  // biased var
        const float mean_abs = t[2] * invS;
        const float missing  = t[3] * invS;
        const float n_unique = t[4];
        const float max_abs  = t[5];
        float between = 0.f;
        #pragma unroll
        for (int c = 0; c < NC; c++) {
            const float cnt = (float)cnts[c];
            const float cm  = t[6 + c] / fmaxf(cnt, 1.f);
            const float d   = cm - gmean;
            between += cnt * d * d;
        }
        between *= invS;                                   // counts sum to NS
        const float target = between / fmaxf(variance, 1e-6f);
        float st[6] = { target, missing, n_unique * invS, variance, mean_abs, max_abs };
        #pragma unroll
        for (int i = 0; i < 6; i++) {
            float v = st[i];
            if (!(fabsf(v) < INFINITY)) v = 0.f;           // nan_to_num(nan/±inf -> 0)
            stats_s[i] = v;
        }
    }
    __syncthreads();

    // MLP epilogue: 6 -> 64 (exact GELU) -> 128
    if (tid < 64) {
        float z = b1[tid];
        #pragma unroll
        for (int i = 0; i < 6; i++) z = fmaf(stats_s[i], w1[i * 64 + tid], z);
        h_s[tid] = 0.5f * z * (1.f + erff(z * 0.70710678118654752440f));
    }
    __syncthreads();
    if (tid < 128) {
        float o = b2[tid];
        #pragma unroll
        for (int j = 0; j < 64; j++) o = fmaf(h_s[j], w2[j * 128 + tid], o);
        out[(size_t)g * 128 + tid] = o;
    }
}

extern "C" void kernel_launch(void* const* d_in, const int* in_sizes, int n_in,
                              void* d_out, int out_size, void* d_ws, size_t ws_size,
                              hipStream_t stream) {
    const float* X  = (const float*)d_in[0];
    const int*   y  = (const int*)d_in[1];
    const float* w1 = (const float*)d_in[2];
    const float* b1 = (const float*)d_in[3];
    const float* w2 = (const float*)d_in[4];
    const float* b2 = (const float*)d_in[5];
    float* out = (float*)d_out;

    fused_all_kernel<<<NB * NF, 256, 0, stream>>>(X, y, w1, b1, w2, b2, out);
}